// Round 2
// baseline (33630.722 us; speedup 1.0000x reference)
//
#include <hip/hip_runtime.h>
#include <hip/hip_bf16.h>

#define SEQ 512
#define BATCH 64
#define NIN 1024
#define HIDN 1024

typedef __attribute__((ext_vector_type(8))) short short8;
typedef __attribute__((ext_vector_type(4))) float floatx4;

__device__ __forceinline__ short f2bf(float f) {
  return __builtin_bit_cast(short, __float2bfloat16(f));
}

// Build WC[j][0..2047] = bf16(W_ih[j][:]) || bf16(W_hh[j][:]), bias = b_ih + b_hh
__global__ __launch_bounds__(256) void prep_kernel(
    const float* __restrict__ Wih, const float* __restrict__ Whh,
    const float* __restrict__ bih, const float* __restrict__ bhh,
    short* __restrict__ WC, float* __restrict__ bias) {
  int idx = blockIdx.x * 256 + threadIdx.x;   // 0 .. 1024*2048-1
  int j = idx >> 11;
  int k = idx & 2047;
  float v = (k < NIN) ? Wih[j * NIN + k] : Whh[j * HIDN + (k - NIN)];
  WC[idx] = f2bf(v);
  if (idx < HIDN) bias[idx] = bih[idx] + bhh[idx];
}

// One recurrent step, fused x-projection:
//   out_s[b][j] = tanh( sum_k x_s[b][k]*W_ih[j][k] + sum_k h_prev[b][k]*W_hh[j][k] + bias[j] )
// Grid: 16 blocks (j-tile 64) x 256 threads (4 waves). Wave w owns b-rows [16w,16w+16),
// all 64 j of the block, via 4 MFMA positions (16x16x32 bf16), K = 2048 fused.
// A-fragments converted fp32->bf16 on the fly (x from input, h from out[s-1]).
__global__ __launch_bounds__(256) void step_kernel(
    const float* __restrict__ x_s, const float* __restrict__ h_prev,
    float* __restrict__ out_s, const short* __restrict__ WC,
    const float* __restrict__ bias) {
  const int tid  = threadIdx.x;
  const int wave = tid >> 6;
  const int lane = tid & 63;
  const int lo   = lane & 15;   // A-row / B-col / D-col within tile
  const int kg   = lane >> 4;   // K-group (8 elems each)

  const int j0   = blockIdx.x * 64;
  const int brow = wave * 16 + lo;  // global batch row this lane loads A for

  floatx4 acc[4];
  #pragma unroll
  for (int n = 0; n < 4; ++n) acc[n] = (floatx4){0.f, 0.f, 0.f, 0.f};

  const int kend = (h_prev == nullptr) ? NIN : (NIN + HIDN);
  for (int k0 = 0; k0 < kend; k0 += 32) {
    const int kidx = k0 + kg * 8;
    // ---- A fragment: 8 consecutive k of row `brow`, fp32 -> bf16 ----
    const float* asrc = (k0 < NIN) ? (x_s + (size_t)brow * NIN + kidx)
                                   : (h_prev + (size_t)brow * HIDN + (kidx - NIN));
    const floatx4 f0 = *(const floatx4*)(asrc);
    const floatx4 f1 = *(const floatx4*)(asrc + 4);
    short8 af;
    af[0] = f2bf(f0[0]); af[1] = f2bf(f0[1]); af[2] = f2bf(f0[2]); af[3] = f2bf(f0[3]);
    af[4] = f2bf(f1[0]); af[5] = f2bf(f1[1]); af[6] = f2bf(f1[2]); af[7] = f2bf(f1[3]);
    // ---- B fragments (bf16-native, 16B per lane) + MFMA ----
    #pragma unroll
    for (int n = 0; n < 4; ++n) {
      const short8 bf = *(const short8*)(WC + (((size_t)(j0 + n * 16 + lo)) << 11) + kidx);
      acc[n] = __builtin_amdgcn_mfma_f32_16x16x32_bf16(af, bf, acc[n], 0, 0, 0);
    }
  }

  // Epilogue: D layout col=lane&15, row=(lane>>4)*4+r. Add bias, tanh, store fp32.
  #pragma unroll
  for (int n = 0; n < 4; ++n) {
    const int jc = j0 + n * 16 + lo;
    const float bb = bias[jc];
    #pragma unroll
    for (int r = 0; r < 4; ++r) {
      const int br = wave * 16 + kg * 4 + r;
      out_s[(size_t)br * HIDN + jc] = tanhf(acc[n][r] + bb);
    }
  }
}

extern "C" void kernel_launch(void* const* d_in, const int* in_sizes, int n_in,
                              void* d_out, int out_size, void* d_ws, size_t ws_size,
                              hipStream_t stream) {
  (void)in_sizes; (void)n_in; (void)out_size; (void)ws_size;
  const float* input = (const float*)d_in[0];
  const float* Wih   = (const float*)d_in[1];
  const float* Whh   = (const float*)d_in[2];
  const float* bih   = (const float*)d_in[3];
  const float* bhh   = (const float*)d_in[4];
  float* out = (float*)d_out;

  short* WC   = (short*)d_ws;                                        // 1024*2048 bf16 = 4 MB
  float* bias = (float*)((char*)d_ws + (size_t)HIDN * 2048 * sizeof(short));

  prep_kernel<<<(HIDN * 2048) / 256, 256, 0, stream>>>(Wih, Whh, bih, bhh, WC, bias);

  for (int s = 0; s < SEQ; ++s) {
    const float* xs = input + (size_t)s * BATCH * NIN;
    const float* hp = (s == 0) ? nullptr : out + (size_t)(s - 1) * BATCH * HIDN;
    step_kernel<<<16, 256, 0, stream>>>(xs, hp, out + (size_t)s * BATCH * HIDN, WC, bias);
  }
}

// Round 3
// 10021.032 us; speedup vs baseline: 3.3560x; 3.3560x over previous
//
#include <hip/hip_runtime.h>
#include <hip/hip_bf16.h>
#include <math.h>

#define SEQ 512
#define BATCH 64
#define NIN 1024
#define HIDN 1024
#define NBLK 64   // persistent blocks
#define JT 16     // j-columns per persistent block

typedef __attribute__((ext_vector_type(8))) short short8;
typedef __attribute__((ext_vector_type(4))) float floatx4;

__device__ __forceinline__ short f2bf(float f) {
  return __builtin_bit_cast(short, __float2bfloat16(f));
}

// ---- ws layout (bytes) ----
//  0x000000  WCih [1024*1024] bf16   (2 MB)
//  0x200000  WChh [1024*1024] bf16   (2 MB)
//  0x400000  bias [1024] f32         (4 KB)
//  0x401000  hb0  [64*1024] bf16     (128 KB)
//  0x421000  hb1  [64*1024] bf16     (128 KB)
//  0x441000  cnt  [1] u32
#define OFF_WCHH 0x200000
#define OFF_BIAS 0x400000
#define OFF_HB0  0x401000
#define OFF_HB1  0x421000
#define OFF_CNT  0x441000

// Convert weights to bf16, sum biases, zero h-init buffer and barrier counter.
// MUST run every launch: ws is re-poisoned 0xAA before each timed call.
__global__ __launch_bounds__(256) void prep_kernel(
    const float* __restrict__ Wih, const float* __restrict__ Whh,
    const float* __restrict__ bih, const float* __restrict__ bhh,
    short* __restrict__ WCih, short* __restrict__ WChh, float* __restrict__ bias,
    short* __restrict__ hb1, unsigned* __restrict__ cnt) {
  int idx = blockIdx.x * 256 + threadIdx.x;        // 0 .. 2*1024*1024-1
  if (idx < (1 << 20)) WCih[idx] = f2bf(Wih[idx]);
  else                 WChh[idx - (1 << 20)] = f2bf(Whh[idx - (1 << 20)]);
  if (idx < HIDN) bias[idx] = bih[idx] + bhh[idx];
  if (idx < BATCH * HIDN) hb1[idx] = 0;            // h_{-1} = 0 (step 0 reads hb1)
  if (idx == 0) *cnt = 0;
}

// Bulk x-projection: out[s*64+b][j] = x[s,b,:]*W_ih[j,:] + (b_ih[j]+b_hh[j])
// M=32768, N=1024, K=1024.  BM=128, BN=256, 4 waves each own 64x128 (4x8 frags).
__global__ __launch_bounds__(256) void xproj_kernel(
    const float* __restrict__ x, const short* __restrict__ WCih,
    const float* __restrict__ bias, float* __restrict__ out) {
  const int tid = threadIdx.x;
  const int wave = tid >> 6, lane = tid & 63, lo = lane & 15, kg = lane >> 4;
  const int m0 = (blockIdx.x >> 2) * 128;
  const int n0 = (blockIdx.x & 3) * 256;
  const int mw = m0 + (wave >> 1) * 64;
  const int nw = n0 + (wave & 1) * 128;

  floatx4 acc[4][8];
  #pragma unroll
  for (int mi = 0; mi < 4; ++mi)
    #pragma unroll
    for (int ni = 0; ni < 8; ++ni) acc[mi][ni] = (floatx4){0.f, 0.f, 0.f, 0.f};

  for (int k0 = 0; k0 < NIN; k0 += 32) {
    const int kidx = k0 + kg * 8;
    short8 a[4];
    #pragma unroll
    for (int mi = 0; mi < 4; ++mi) {
      const float* asrc = x + (size_t)(mw + mi * 16 + lo) * NIN + kidx;
      const floatx4 f0 = *(const floatx4*)asrc;
      const floatx4 f1 = *(const floatx4*)(asrc + 4);
      short8 t;
      t[0] = f2bf(f0[0]); t[1] = f2bf(f0[1]); t[2] = f2bf(f0[2]); t[3] = f2bf(f0[3]);
      t[4] = f2bf(f1[0]); t[5] = f2bf(f1[1]); t[6] = f2bf(f1[2]); t[7] = f2bf(f1[3]);
      a[mi] = t;
    }
    short8 b[8];
    #pragma unroll
    for (int ni = 0; ni < 8; ++ni)
      b[ni] = *(const short8*)(WCih + ((size_t)(nw + ni * 16 + lo) << 10) + kidx);
    #pragma unroll
    for (int mi = 0; mi < 4; ++mi)
      #pragma unroll
      for (int ni = 0; ni < 8; ++ni)
        acc[mi][ni] = __builtin_amdgcn_mfma_f32_16x16x32_bf16(a[mi], b[ni], acc[mi][ni], 0, 0, 0);
  }

  // D layout: col = lane&15, row = (lane>>4)*4 + r   (round-0 verified)
  #pragma unroll
  for (int ni = 0; ni < 8; ++ni) {
    const int col = nw + ni * 16 + lo;
    const float bb = bias[col];
    #pragma unroll
    for (int mi = 0; mi < 4; ++mi)
      #pragma unroll
      for (int r = 0; r < 4; ++r) {
        const int row = mw + mi * 16 + kg * 4 + r;
        out[(size_t)row * HIDN + col] = acc[mi][ni][r] + bb;
      }
  }
}

// Persistent recurrent kernel: 64 blocks, block jb owns columns [16jb,16jb+16).
// W_hh tile (16x1024 bf16, 32KB) lives in LDS, XOR-swizzled so the wave's
// 64-lane ds_read_b128 (bank quad = kg^(lo&7)) is conflict-free.
// h ping-pongs between hb0/hb1 (bf16). One device-scope barrier per step.
__global__ __launch_bounds__(256, 1) void rnn_persist(
    const short* __restrict__ WChh, float* __restrict__ out,
    short* __restrict__ hb0, short* __restrict__ hb1, unsigned* cnt) {
  __shared__ short wlds[JT * HIDN];  // 32 KB
  const int tid = threadIdx.x;
  const int wave = tid >> 6, lane = tid & 63, lo = lane & 15, kg = lane >> 4;
  const int j0 = blockIdx.x * JT;

  // Stage + swizzle W_hh tile (once).
  for (int c = tid; c < JT * HIDN / 8; c += 256) {   // 2048 chunks of 8 bf16
    const int j = c >> 7;
    const int kc = (c & 127) * 8;
    const short8 v = *(const short8*)(WChh + ((size_t)(j0 + j) << 10) + kc);
    const int byte = (j * 2048 + kc * 2) ^ ((j & 7) << 4);
    *(short8*)((char*)wlds + byte) = v;
  }
  __syncthreads();

  const int bb  = lo * 2048 + kg * 16;   // B-frag base byte (pre-swizzle)
  const int swz = (lo & 7) << 4;
  const int brow = wave * 16 + lo;       // batch row whose A-frag this lane loads
  const int orow = wave * 16 + kg * 4;   // first of 4 output rows this lane owns
  const int jc = j0 + lo;                // output column this lane owns

  for (int s = 0; s < SEQ; ++s) {
    const short* hr = (s & 1) ? hb0 : hb1;   // read  h_{s-1}
    short*       hw = (s & 1) ? hb1 : hb0;   // write h_s
    float* outs = out + (size_t)s * BATCH * HIDN;

    // Prefetch xp (independent of h) so it overlaps the K-loop.
    float xp[4];
    #pragma unroll
    for (int r = 0; r < 4; ++r)
      xp[r] = outs[(size_t)(orow + r) * HIDN + jc];

    floatx4 acc0 = (floatx4){0.f, 0.f, 0.f, 0.f};
    floatx4 acc1 = (floatx4){0.f, 0.f, 0.f, 0.f};
    const short* hrow = hr + ((size_t)brow << 10) + kg * 8;
    #pragma unroll
    for (int k0 = 0; k0 < HIDN; k0 += 64) {
      const short8 a0 = *(const short8*)(hrow + k0);
      const short8 a1 = *(const short8*)(hrow + k0 + 32);
      const short8 b0 = *(const short8*)((const char*)wlds + ((bb + 2 * k0) ^ swz));
      const short8 b1 = *(const short8*)((const char*)wlds + ((bb + 2 * (k0 + 32)) ^ swz));
      acc0 = __builtin_amdgcn_mfma_f32_16x16x32_bf16(a0, b0, acc0, 0, 0, 0);
      acc1 = __builtin_amdgcn_mfma_f32_16x16x32_bf16(a1, b1, acc1, 0, 0, 0);
    }
    const floatx4 acc = acc0 + acc1;

    #pragma unroll
    for (int r = 0; r < 4; ++r) {
      const float h = tanhf(acc[r] + xp[r]);
      outs[(size_t)(orow + r) * HIDN + jc] = h;
      hw[((size_t)(orow + r) << 10) + jc] = f2bf(h);
    }

    // Grid barrier: monotonic counter, device scope, release/acquire.
    __threadfence();
    __syncthreads();
    if (tid == 0) {
      __hip_atomic_fetch_add(cnt, 1u, __ATOMIC_RELEASE, __HIP_MEMORY_SCOPE_AGENT);
      const unsigned target = (unsigned)NBLK * (unsigned)(s + 1);
      int guard = 0;
      while (__hip_atomic_load(cnt, __ATOMIC_ACQUIRE, __HIP_MEMORY_SCOPE_AGENT) < target) {
        if (++guard > (1 << 18)) break;   // failsafe: wrong answer beats a hang
        __builtin_amdgcn_s_sleep(8);
      }
    }
    __syncthreads();
    __threadfence();   // all threads: invalidate stale L1/L2 before reading new h
  }
}

extern "C" void kernel_launch(void* const* d_in, const int* in_sizes, int n_in,
                              void* d_out, int out_size, void* d_ws, size_t ws_size,
                              hipStream_t stream) {
  (void)in_sizes; (void)n_in; (void)out_size; (void)ws_size;
  const float* input = (const float*)d_in[0];
  const float* Wih   = (const float*)d_in[1];
  const float* Whh   = (const float*)d_in[2];
  const float* bih   = (const float*)d_in[3];
  const float* bhh   = (const float*)d_in[4];
  float* out = (float*)d_out;

  char* ws = (char*)d_ws;
  short*    WCih = (short*)ws;
  short*    WChh = (short*)(ws + OFF_WCHH);
  float*    bias = (float*)(ws + OFF_BIAS);
  short*    hb0  = (short*)(ws + OFF_HB0);
  short*    hb1  = (short*)(ws + OFF_HB1);
  unsigned* cnt  = (unsigned*)(ws + OFF_CNT);

  prep_kernel<<<(2 * 1024 * 1024) / 256, 256, 0, stream>>>(
      Wih, Whh, bih, bhh, WCih, WChh, bias, hb1, cnt);

  // M=32768/BM=128 -> 256 m-tiles, N=1024/BN=256 -> 4 n-tiles
  xproj_kernel<<<256 * 4, 256, 0, stream>>>(input, WCih, bias, out);

  rnn_persist<<<NBLK, 256, 0, stream>>>(WChh, out, hb0, hb1, cnt);
}